// Round 15
// baseline (602.913 us; speedup 1.0000x reference)
//
#include <hip/hip_runtime.h>

// ---- geometry ----
#define GSZ 32
#define NPTS (1<<20)             // 32^4

// padded line tensors: [34][34][34] lines
// XB: bf16 [34][34][34][32]              (input, 64B lines)
// X2/X3: bf16 [34][34][34][32*10]        (PACKED 10 ch, 640B lines)
#define XB_FLOATS ((size_t)34*34*34*16)     //   628,864 float-units
#define XTP ((size_t)34*34*34*160)          // 6,288,640 float-units per packed tensor

// per-BATCH slot: XB | X2A | X2B | X3A | X3B  (+16 float pad for 12B tail overrun)
#define OFF_XB  ((size_t)0)
#define OFF_X2  (XB_FLOATS)
#define BSLOT   (XB_FLOATS + 4*XTP + 16)    // 25,783,456 floats = 103.1 MB

// packed-B region (u32 units): wsB2 2x6912 @0 | wsB3 2x2304 @13824 | wsB1 2x768 @18432
#define WSB_FLOATS 20480
#define NHALO 6536         // halo lines in 34^3 (any coord 0 or 33)

typedef __attribute__((ext_vector_type(8)))  short bf16x8;
typedef __attribute__((ext_vector_type(16))) float f32x16;
typedef __attribute__((ext_vector_type(4)))  unsigned uintx4;

__device__ __forceinline__ unsigned short f2bf(float f) {
    union { float f; unsigned u; } v; v.f = f;
    unsigned r = v.u + 0x7FFFu + ((v.u >> 16) & 1u);   // RNE
    return (unsigned short)(r >> 16);
}

// ---------------------------------------------------------------
// one-shot weight pack, all three layers, both branches.
// branch 1 uses W'[d1,d2,d3,d4]=W[d3,d4,d1,d2].
// B rows k>=10 are EXACT ZEROS — they multiply the packed-A garbage lanes.
// ---------------------------------------------------------------
__global__ void k_bpack_all(const float* __restrict__ W1, const float* __restrict__ W2,
                            const float* __restrict__ W3,
                            unsigned* __restrict__ wsB2, unsigned* __restrict__ wsB3,
                            unsigned* __restrict__ wsB1) {
    int t = threadIdx.x;
    int lane = t & 63, j = t >> 6;
    int n = lane & 31, kh = lane >> 5;
    // conv2
    for (int br = 0; br < 2; ++br)
        for (int g = 0; g < 27; ++g) {
            int d1 = g / 9, d2 = (g / 3) % 3, d3 = g % 3;
            unsigned v = 0;
            for (int e = 0; e < 2; ++e) {
                int k = kh * 8 + 2 * j + e;
                unsigned short h = 0;
                if (k < 10 && n < 30) {
                    int co = n % 10, d4 = n / 10;
                    int tap = br == 0 ? ((d1 * 3 + d2) * 3 + d3) * 3 + d4
                                      : ((d3 * 3 + d4) * 3 + d1) * 3 + d2;
                    h = f2bf(W2[(co * 10 + k) * 81 + tap]);
                }
                v |= (unsigned)h << (16 * e);
            }
            wsB2[((br * 27 + g) * 64 + lane) * 4 + j] = v;
        }
    // conv3
    for (int br = 0; br < 2; ++br)
        for (int g = 0; g < 9; ++g) {
            int d1 = g / 3, d2 = g % 3;
            unsigned v = 0;
            for (int e = 0; e < 2; ++e) {
                int k = kh * 8 + 2 * j + e;
                unsigned short h = 0;
                if (k < 10 && n < 9) {
                    int d3 = n / 3, d4 = n % 3;
                    int tap = br == 0 ? ((d1 * 3 + d2) * 3 + d3) * 3 + d4
                                      : ((d3 * 3 + d4) * 3 + d1) * 3 + d2;
                    h = f2bf(W3[k * 81 + tap]);
                }
                v |= (unsigned)h << (16 * e);
            }
            wsB3[((br * 9 + g) * 64 + lane) * 4 + j] = v;
        }
    // conv1: g = d3; B[kap=(d1,d2)][n=(d4,co)]
    for (int br = 0; br < 2; ++br)
        for (int g = 0; g < 3; ++g) {
            unsigned v = 0;
            for (int e = 0; e < 2; ++e) {
                int kap = kh * 8 + 2 * j + e;
                unsigned short h = 0;
                if (kap < 9 && n < 30) {
                    int co = n % 10, d4 = n / 10;
                    int d1 = kap / 3, d2 = kap % 3;
                    int tap = br == 0 ? ((d1 * 3 + d2) * 3 + g) * 3 + d4
                                      : ((g * 3 + d4) * 3 + d1) * 3 + d2;
                    h = f2bf(W1[co * 81 + tap]);
                }
                v |= (unsigned)h << (16 * e);
            }
            wsB1[((br * 3 + g) * 64 + lane) * 4 + j] = v;
        }
}

// ---------------------------------------------------------------
// zero halo lines of XB / X2A / X2B / X3A / X3B for each batch slot
// ---------------------------------------------------------------
__global__ __launch_bounds__(256) void k_zero_halo(float* __restrict__ ws) {
    int wid = blockIdx.x * 4 + (threadIdx.x >> 6);
    if (wid >= NHALO) return;
    int lane = threadIdx.x & 63;
    int i, j, k;
    if (wid < 2312) {
        i = (wid < 1156) ? 0 : 33;
        int r = wid % 1156; j = r / 34; k = r % 34;
    } else if (wid < 4488) {
        int r = wid - 2312;
        i = 1 + r / 68;
        int r2 = r % 68;
        j = (r2 < 34) ? 0 : 33;
        k = r2 % 34;
    } else {
        int r = wid - 4488;
        i = 1 + r / 64;
        int r2 = r % 64;
        j = 1 + (r2 >> 1);
        k = (r2 & 1) ? 33 : 0;
    }
    size_t line = (size_t)(i * 34 + j) * 34 + k;
    float* slot = ws + (size_t)blockIdx.y * BSLOT;
    uintx4 z4 = {0u, 0u, 0u, 0u};
    if (lane < 40) {
        char* base = (char*)(slot + OFF_X2) + line * 640 + lane * 16;
#pragma unroll
        for (int tns = 0; tns < 4; ++tns)
            *(uintx4*)(base + (size_t)tns * (XTP * 4)) = z4;
    }
    if (lane < 4) ((uintx4*)((char*)(slot + OFF_XB) + line * 64))[lane] = z4;
}

// ---------------------------------------------------------------
// copy input to bf16 padded XB (identity only — one per batch), x4 vectorized
// ---------------------------------------------------------------
__global__ __launch_bounds__(256) void k_copy_in(const float* __restrict__ x,
                                                 float* __restrict__ ws, int b0) {
    int b = b0 + blockIdx.z;
    int gid = blockIdx.x * 256 + threadIdx.x;   // over NPTS/4
    int l0 = (gid & 7) * 4;
    int k = (gid >> 3) & 31, j = (gid >> 8) & 31, i = gid >> 13;
    float4 v = *(const float4*)(x + (size_t)b * NPTS + (size_t)gid * 4);
    ushort4 h;
    h.x = f2bf(v.x); h.y = f2bf(v.y); h.z = f2bf(v.z); h.w = f2bf(v.w);
    unsigned short* XB = (unsigned short*)(ws + (size_t)blockIdx.z * BSLOT + OFF_XB);
    *(ushort4*)(XB + ((size_t)(((i + 1) * 34 + (j + 1)) * 34 + (k + 1))) * 32 + l0) = h;
}

// ---------------------------------------------------------------
// conv1 via MFMA 32x32x16: K=(d1,d2) 9-of-16, N=(d4,co), d3 folded via kk/m.
// writes PACKED X2. z = (batch<<2) | (branch<<1) | khalf   (R10 version)
// ---------------------------------------------------------------
__global__ __launch_bounds__(256) void k_conv1m(const unsigned* __restrict__ wsB1,
                                                const float* __restrict__ B1,
                                                float* ws) {
    __shared__ float epi[4][34 * 33];
    int t = threadIdx.x, lane = t & 63, wv = t >> 6;
    int zb = blockIdx.z >> 2, br = (blockIdx.z >> 1) & 1, w = blockIdx.z & 1;
    int bid = blockIdx.x;
    int s = ((bid & 7) << 7) | (bid >> 3);
    int i = s >> 5, j = s & 31;
    int k0g = w * 16 + wv * 4;           // padded-k of kk=0
    int q = lane & 31, half = lane >> 5;

    float bias[8];
#pragma unroll
    for (int e = 0; e < 8; ++e) {
        int co = half * 8 + e;
        bias[e] = (co < 10) ? B1[co] : 0.f;
    }
    if (lane < 33) { epi[wv][lane] = 0.f; epi[wv][33 * 33 + lane] = 0.f; }

    float* slot = ws + (size_t)zb * BSLOT;
    const unsigned short* XB = (const unsigned short*)(slot + OFF_XB);
    const unsigned short* xb = XB + ((size_t)((i * 34 + j) * 34 + k0g)) * 32 + q;
    const bf16x8* Bg = (const bf16x8*)(wsB1 + br * 3 * 64 * 4);

    bf16x8 A[6];
    if (half == 0) {
#pragma unroll
        for (int kk = 0; kk < 6; ++kk) {
            bf16x8 a;
#pragma unroll
            for (int e = 0; e < 8; ++e) {
                const int d1 = e / 3, d2 = e % 3;
                a[e] = (short)xb[(size_t)(d1 * 34 + d2) * 1088 + kk * 32];
            }
            A[kk] = a;
        }
    } else {
#pragma unroll
        for (int kk = 0; kk < 6; ++kk) {
            bf16x8 a = {};
            a[0] = (short)xb[(size_t)(2 * 34 + 2) * 1088 + kk * 32];
            A[kk] = a;
        }
    }
    bf16x8 Bf[3];
#pragma unroll
    for (int d3 = 0; d3 < 3; ++d3) Bf[d3] = Bg[d3 * 64 + lane];

    f32x16 D[4] = {};
#pragma unroll
    for (int kk = 0; kk < 6; ++kk)
#pragma unroll
        for (int m = 0; m < 4; ++m) {
            int d3 = kk - m;
            if (d3 >= 0 && d3 < 3)
                D[m] = __builtin_amdgcn_mfma_f32_32x32x16_bf16(A[kk], Bf[d3], D[m], 0, 0, 0);
        }

    // epilogue: d4 shift-add, bias, relu, packed store
    float* epw = epi[wv];
    char* X2b = (char*)(slot + OFF_X2 + (size_t)br * XTP);
#pragma unroll
    for (int m = 0; m < 4; ++m) {
#pragma unroll
        for (int r = 0; r < 16; ++r) {
            int row = (r & 3) + 8 * (r >> 2) + 4 * half;
            epw[(row + 1) * 33 + q] = D[m][r];
        }
        size_t lb = ((size_t)(((i + 1) * 34 + (j + 1)) * 34 + (k0g + m + 1))) * 640 + q * 20;
        if (half == 0) {
            unsigned u[4];
#pragma unroll
            for (int e = 0; e < 4; ++e) {
                unsigned short h2[2];
#pragma unroll
                for (int xx = 0; xx < 2; ++xx) {
                    int co = 2 * e + xx;
                    float v = bias[2 * e + xx];
#pragma unroll
                    for (int ss = 0; ss < 3; ++ss)
                        v += epw[(q + ss) * 33 + ss * 10 + co];
                    h2[xx] = f2bf(fmaxf(v, 0.f));
                }
                u[e] = (unsigned)h2[0] | ((unsigned)h2[1] << 16);
            }
            uintx4 u4 = {u[0], u[1], u[2], u[3]};
            *(uintx4*)(X2b + lb) = u4;
        } else {
            unsigned short h2[2];
#pragma unroll
            for (int xx = 0; xx < 2; ++xx) {
                int co = 8 + xx;
                float v = bias[xx];
#pragma unroll
                for (int ss = 0; ss < 3; ++ss)
                    v += epw[(q + ss) * 33 + ss * 10 + co];
                h2[xx] = f2bf(fmaxf(v, 0.f));
            }
            *(unsigned*)(X2b + lb + 16) = (unsigned)h2[0] | ((unsigned)h2[1] << 16);
        }
    }
}

// ---------------------------------------------------------------
// conv2 via MFMA 32x32x16, N=(d4,co). PACKED 640B A-lines, uniform loads.
// J-PAIRED BLOCK: 512 threads = 2 j-values x 4 k-waves. Adjacent j's share
// 2 of 3 tap columns -> co-resident waves hit L1 instead of refetching L2
// (L2 A-traffic x0.67). A ping-pong prefetch (R10); B from L1; epi LDS only.
// z = (batch<<2) | (branch<<1) | khalf
// ---------------------------------------------------------------
__global__ __launch_bounds__(512) void k_conv2m(const unsigned* __restrict__ wsB,
                                                const float* __restrict__ B2,
                                                float* ws) {
    __shared__ float epi[8][34 * 33];

    int t = threadIdx.x;
    int lane = t & 63, wv = t >> 6;          // wv 0..7
    int jj = wv >> 2, wvk = wv & 3;
    int zb = blockIdx.z >> 2, br = (blockIdx.z >> 1) & 1, w = blockIdx.z & 1;
    int bid = blockIdx.x;                    // 0..511
    int s = ((bid & 7) << 6) | (bid >> 3);   // XCD-chunked swizzle over 512
    int i = s >> 4, jp = s & 15;
    int j = jp * 2 + jj;
    int k0 = (w * 4 + wvk) * 4;
    int q = lane & 31, half = lane >> 5;

    if (lane < 33) { epi[wv][lane] = 0.f; epi[wv][33 * 33 + lane] = 0.f; }

    float bias[8];
#pragma unroll
    for (int e = 0; e < 8; ++e) {
        int co = half * 8 + e;
        bias[e] = (co < 10) ? B2[co] : 0.f;
    }

    float* slot = ws + (size_t)zb * BSLOT;
    const char* X2b = (const char*)(slot + OFF_X2 + (size_t)br * XTP)
                      + q * 20 + half * 16 + (size_t)k0 * 640;
    const bf16x8* Bg = (const bf16x8*)(wsB + br * 27 * 64 * 4);

    bf16x8 A[2][6];
    // preload tap 0
#pragma unroll
    for (int kk = 0; kk < 6; ++kk)
        A[0][kk] = *(const bf16x8*)(X2b + ((size_t)(i * 34 + j) * 34) * 640 + kk * 640);

    f32x16 D[4] = {};

#pragma unroll
    for (int g = 0; g < 9; ++g) {
        if (g < 8) {
            const int gn = g + 1, d1n = gn / 3, d2n = gn % 3;
            const char* pn = X2b + ((size_t)((i + d1n) * 34 + (j + d2n)) * 34) * 640;
#pragma unroll
            for (int kk = 0; kk < 6; ++kk)
                A[gn & 1][kk] = *(const bf16x8*)(pn + kk * 640);
        }
        bf16x8 Bf[3];
#pragma unroll
        for (int d3 = 0; d3 < 3; ++d3)
            Bf[d3] = Bg[(g * 3 + d3) * 64 + lane];
#pragma unroll
        for (int kk = 0; kk < 6; ++kk)
#pragma unroll
            for (int m = 0; m < 4; ++m) {
                int d3 = kk - m;
                if (d3 >= 0 && d3 < 3)
                    D[m] = __builtin_amdgcn_mfma_f32_32x32x16_bf16(A[g & 1][kk], Bf[d3], D[m], 0, 0, 0);
            }
    }

    // epilogue: shift-add along d4, bias, relu, packed store to X3
    float* epw = epi[wv];
    char* X3b = (char*)(slot + OFF_X2 + (size_t)(2 + br) * XTP);
#pragma unroll
    for (int m = 0; m < 4; ++m) {
#pragma unroll
        for (int r = 0; r < 16; ++r) {
            int row = (r & 3) + 8 * (r >> 2) + 4 * half;   // D row = l
            epw[(row + 1) * 33 + q] = D[m][r];             // col = n
        }
        size_t lb = ((size_t)(((i + 1) * 34 + (j + 1)) * 34 + (k0 + m + 1))) * 640 + q * 20;
        if (half == 0) {
            unsigned u[4];
#pragma unroll
            for (int e = 0; e < 4; ++e) {
                unsigned short h2[2];
#pragma unroll
                for (int xx = 0; xx < 2; ++xx) {
                    int co = 2 * e + xx;
                    float v = bias[2 * e + xx];
#pragma unroll
                    for (int ss = 0; ss < 3; ++ss)
                        v += epw[(q + ss) * 33 + ss * 10 + co];
                    h2[xx] = f2bf(fmaxf(v, 0.f));
                }
                u[e] = (unsigned)h2[0] | ((unsigned)h2[1] << 16);
            }
            uintx4 u4 = {u[0], u[1], u[2], u[3]};
            *(uintx4*)(X3b + lb) = u4;
        } else {
            unsigned short h2[2];
#pragma unroll
            for (int xx = 0; xx < 2; ++xx) {
                int co = 8 + xx;
                float v = bias[xx];
#pragma unroll
                for (int ss = 0; ss < 3; ++ss)
                    v += epw[(q + ss) * 33 + ss * 10 + co];
                h2[xx] = f2bf(fmaxf(v, 0.f));
            }
            *(unsigned*)(X3b + lb + 16) = (unsigned)h2[0] | ((unsigned)h2[1] << 16);
        }
    }
}

// ---------------------------------------------------------------
// conv3 via MFMA, N=(d3,d4), 10->1, ReLU. BOTH branches in one block:
// out = relu(convA+b) + relu(convB+b), single coalesced store.
// J-PAIRED BLOCK (512 threads) like conv2m. B from L1; barrier-free.
// z = (batch<<1) | khalf
// ---------------------------------------------------------------
__global__ __launch_bounds__(512) void k_conv3m(const unsigned* __restrict__ wsB3,
                                                const float* __restrict__ B3,
                                                float* ws, float* __restrict__ out,
                                                int b0) {
    __shared__ float epi[8][6 * 34 * 9];

    int t = threadIdx.x;
    int lane = t & 63, wv = t >> 6;          // 0..7
    int jj = wv >> 2, wvk = wv & 3;
    int zb = blockIdx.z >> 1, w = blockIdx.z & 1;
    int b = b0 + zb;
    int bid = blockIdx.x;                    // 0..511
    int s = ((bid & 7) << 6) | (bid >> 3);
    int i = s >> 4, jp = s & 15;
    int j = jp * 2 + jj;
    int k0 = (w * 4 + wvk) * 4;
    int q = lane & 31, half = lane >> 5;

    for (int idx = lane; idx < 6 * 9; idx += 64) {
        int rel = idx / 9, c = idx % 9;
        epi[wv][(rel * 34 + 0) * 9 + c] = 0.f;
        epi[wv][(rel * 34 + 33) * 9 + c] = 0.f;
    }

    float* slot = ws + (size_t)zb * BSLOT;
    float* epw = epi[wv];
    float bb = B3[0];
    float vsum[4];

#pragma unroll 1
    for (int br = 0; br < 2; ++br) {
        const char* X3b = (const char*)(slot + OFF_X2 + (size_t)(2 + br) * XTP)
                          + q * 20 + half * 16 + (size_t)k0 * 640;
        const bf16x8* Bg = (const bf16x8*)(wsB3 + br * 9 * 64 * 4);

        f32x16 D[6] = {};

#pragma unroll 1
        for (int g = 0; g < 9; ++g) {
            const char* pg = X3b + ((size_t)((i + g / 3) * 34 + (j + g % 3)) * 34) * 640;
            bf16x8 Bf = Bg[g * 64 + lane];
#pragma unroll
            for (int rel = 0; rel < 6; ++rel) {
                bf16x8 A = *(const bf16x8*)(pg + rel * 640);
                D[rel] = __builtin_amdgcn_mfma_f32_32x32x16_bf16(A, Bf, D[rel], 0, 0, 0);
            }
        }

        if (q < 9) {
#pragma unroll
            for (int rel = 0; rel < 6; ++rel)
#pragma unroll
                for (int r = 0; r < 16; ++r) {
                    int row = (r & 3) + 8 * (r >> 2) + 4 * half;
                    epw[(rel * 34 + row + 1) * 9 + q] = D[rel][r];
                }
        }
        // per-wave LDS: within-wave in-order LDS suffices (no barrier)
#pragma unroll
        for (int m = 0; m < 4; ++m) {
            float v = bb;
#pragma unroll
            for (int d3 = 0; d3 < 3; ++d3)
#pragma unroll
                for (int d4 = 0; d4 < 3; ++d4)
                    v += epw[((m + d3) * 34 + (q + d4)) * 9 + d3 * 3 + d4];
            v = fmaxf(v, 0.f);
            if (br == 0) vsum[m] = v; else vsum[m] += v;
        }
    }

    float* dst = out + (size_t)b * NPTS;
    if (half == 0)
#pragma unroll
        for (int m = 0; m < 4; ++m)
            dst[(size_t)i * 32768 + j * 1024 + (k0 + m) * 32 + q] = vsum[m];
}

// ---------------------------------------------------------------
extern "C" void kernel_launch(void* const* d_in, const int* in_sizes, int n_in,
                              void* d_out, int out_size, void* d_ws, size_t ws_size,
                              hipStream_t stream) {
    const float* x  = (const float*)d_in[0];
    const float* W1 = (const float*)d_in[1];
    const float* b1 = (const float*)d_in[2];
    const float* W2 = (const float*)d_in[3];
    const float* b2 = (const float*)d_in[4];
    const float* W3 = (const float*)d_in[5];
    const float* b3 = (const float*)d_in[6];
    float* out = (float*)d_out;
    float* ws  = (float*)d_ws;
    float* slots = ws + WSB_FLOATS;
    unsigned* wsB2 = (unsigned*)ws;
    unsigned* wsB3 = (unsigned*)ws + 13824;
    unsigned* wsB1 = (unsigned*)ws + 18432;

    size_t slot_bytes = BSLOT * sizeof(float);
    int GB = (int)((ws_size - WSB_FLOATS * 4) / slot_bytes);
    if (GB > 4) GB = 4;
    if (GB < 1) GB = 1;

    k_zero_halo<<<dim3((NHALO + 3) / 4, GB), 256, 0, stream>>>(slots);
    k_bpack_all<<<1, 256, 0, stream>>>(W1, W2, W3, wsB2, wsB3, wsB1);

    for (int b0 = 0; b0 < 4; b0 += GB) {
        int gb = 4 - b0 < GB ? 4 - b0 : GB;
        k_copy_in<<<dim3(1024, 1, gb), 256, 0, stream>>>(x, slots, b0);
        k_conv1m<<<dim3(1024, 1, 4 * gb), 256, 0, stream>>>(wsB1, b1, slots);
        k_conv2m<<<dim3(512, 1, 4 * gb), 512, 0, stream>>>(wsB2, b2, slots);
        k_conv3m<<<dim3(512, 1, 2 * gb), 512, 0, stream>>>(wsB3, b3, slots, out, b0);
    }
}

// Round 16
// 541.566 us; speedup vs baseline: 1.1133x; 1.1133x over previous
//
#include <hip/hip_runtime.h>

// ---- geometry ----
#define GSZ 32
#define NPTS (1<<20)             // 32^4

// padded line tensors: [34][34][34] lines
// XB: bf16 [34][34][34][32]              (input, 64B lines)
// X2/X3: bf16 [34][34][34][32*10]        (PACKED 10 ch, 640B lines)
#define XB_FLOATS ((size_t)34*34*34*16)     //   628,864 float-units
#define XTP ((size_t)34*34*34*160)          // 6,288,640 float-units per packed tensor

// per-BATCH slot: XB | X2A | X2B | X3A | X3B  (+16 float pad for 12B tail overrun)
#define OFF_XB  ((size_t)0)
#define OFF_X2  (XB_FLOATS)
#define BSLOT   (XB_FLOATS + 4*XTP + 16)    // 25,783,456 floats = 103.1 MB

// packed-B region (u32 units): wsB2 2x6912 @0 | wsB3 2x2304 @13824 | wsB1 2x768 @18432
#define WSB_FLOATS 20480
#define NHALO 6536         // halo lines in 34^3 (any coord 0 or 33)

typedef __attribute__((ext_vector_type(8)))  short bf16x8;
typedef __attribute__((ext_vector_type(16))) float f32x16;
typedef __attribute__((ext_vector_type(4)))  unsigned uintx4;

__device__ __forceinline__ unsigned short f2bf(float f) {
    union { float f; unsigned u; } v; v.f = f;
    unsigned r = v.u + 0x7FFFu + ((v.u >> 16) & 1u);   // RNE
    return (unsigned short)(r >> 16);
}

// ---------------------------------------------------------------
// one-shot weight pack, all three layers, both branches.
// branch 1 uses W'[d1,d2,d3,d4]=W[d3,d4,d1,d2].
// B rows k>=10 are EXACT ZEROS — they multiply the packed-A garbage lanes.
// ---------------------------------------------------------------
__global__ void k_bpack_all(const float* __restrict__ W1, const float* __restrict__ W2,
                            const float* __restrict__ W3,
                            unsigned* __restrict__ wsB2, unsigned* __restrict__ wsB3,
                            unsigned* __restrict__ wsB1) {
    int t = threadIdx.x;
    int lane = t & 63, j = t >> 6;
    int n = lane & 31, kh = lane >> 5;
    // conv2
    for (int br = 0; br < 2; ++br)
        for (int g = 0; g < 27; ++g) {
            int d1 = g / 9, d2 = (g / 3) % 3, d3 = g % 3;
            unsigned v = 0;
            for (int e = 0; e < 2; ++e) {
                int k = kh * 8 + 2 * j + e;
                unsigned short h = 0;
                if (k < 10 && n < 30) {
                    int co = n % 10, d4 = n / 10;
                    int tap = br == 0 ? ((d1 * 3 + d2) * 3 + d3) * 3 + d4
                                      : ((d3 * 3 + d4) * 3 + d1) * 3 + d2;
                    h = f2bf(W2[(co * 10 + k) * 81 + tap]);
                }
                v |= (unsigned)h << (16 * e);
            }
            wsB2[((br * 27 + g) * 64 + lane) * 4 + j] = v;
        }
    // conv3
    for (int br = 0; br < 2; ++br)
        for (int g = 0; g < 9; ++g) {
            int d1 = g / 3, d2 = g % 3;
            unsigned v = 0;
            for (int e = 0; e < 2; ++e) {
                int k = kh * 8 + 2 * j + e;
                unsigned short h = 0;
                if (k < 10 && n < 9) {
                    int d3 = n / 3, d4 = n % 3;
                    int tap = br == 0 ? ((d1 * 3 + d2) * 3 + d3) * 3 + d4
                                      : ((d3 * 3 + d4) * 3 + d1) * 3 + d2;
                    h = f2bf(W3[k * 81 + tap]);
                }
                v |= (unsigned)h << (16 * e);
            }
            wsB3[((br * 9 + g) * 64 + lane) * 4 + j] = v;
        }
    // conv1: g = d3; B[kap=(d1,d2)][n=(d4,co)]
    for (int br = 0; br < 2; ++br)
        for (int g = 0; g < 3; ++g) {
            unsigned v = 0;
            for (int e = 0; e < 2; ++e) {
                int kap = kh * 8 + 2 * j + e;
                unsigned short h = 0;
                if (kap < 9 && n < 30) {
                    int co = n % 10, d4 = n / 10;
                    int d1 = kap / 3, d2 = kap % 3;
                    int tap = br == 0 ? ((d1 * 3 + d2) * 3 + g) * 3 + d4
                                      : ((g * 3 + d4) * 3 + d1) * 3 + d2;
                    h = f2bf(W1[co * 81 + tap]);
                }
                v |= (unsigned)h << (16 * e);
            }
            wsB1[((br * 3 + g) * 64 + lane) * 4 + j] = v;
        }
}

// ---------------------------------------------------------------
// zero halo lines of XB / X2A / X2B / X3A / X3B for each batch slot
// ---------------------------------------------------------------
__global__ __launch_bounds__(256) void k_zero_halo(float* __restrict__ ws) {
    int wid = blockIdx.x * 4 + (threadIdx.x >> 6);
    if (wid >= NHALO) return;
    int lane = threadIdx.x & 63;
    int i, j, k;
    if (wid < 2312) {
        i = (wid < 1156) ? 0 : 33;
        int r = wid % 1156; j = r / 34; k = r % 34;
    } else if (wid < 4488) {
        int r = wid - 2312;
        i = 1 + r / 68;
        int r2 = r % 68;
        j = (r2 < 34) ? 0 : 33;
        k = r2 % 34;
    } else {
        int r = wid - 4488;
        i = 1 + r / 64;
        int r2 = r % 64;
        j = 1 + (r2 >> 1);
        k = (r2 & 1) ? 33 : 0;
    }
    size_t line = (size_t)(i * 34 + j) * 34 + k;
    float* slot = ws + (size_t)blockIdx.y * BSLOT;
    uintx4 z4 = {0u, 0u, 0u, 0u};
    if (lane < 40) {
        char* base = (char*)(slot + OFF_X2) + line * 640 + lane * 16;
#pragma unroll
        for (int tns = 0; tns < 4; ++tns)
            *(uintx4*)(base + (size_t)tns * (XTP * 4)) = z4;
    }
    if (lane < 4) ((uintx4*)((char*)(slot + OFF_XB) + line * 64))[lane] = z4;
}

// ---------------------------------------------------------------
// copy input to bf16 padded XB (identity only — one per batch), x4 vectorized
// ---------------------------------------------------------------
__global__ __launch_bounds__(256) void k_copy_in(const float* __restrict__ x,
                                                 float* __restrict__ ws, int b0) {
    int b = b0 + blockIdx.z;
    int gid = blockIdx.x * 256 + threadIdx.x;   // over NPTS/4
    int l0 = (gid & 7) * 4;
    int k = (gid >> 3) & 31, j = (gid >> 8) & 31, i = gid >> 13;
    float4 v = *(const float4*)(x + (size_t)b * NPTS + (size_t)gid * 4);
    ushort4 h;
    h.x = f2bf(v.x); h.y = f2bf(v.y); h.z = f2bf(v.z); h.w = f2bf(v.w);
    unsigned short* XB = (unsigned short*)(ws + (size_t)blockIdx.z * BSLOT + OFF_XB);
    *(ushort4*)(XB + ((size_t)(((i + 1) * 34 + (j + 1)) * 34 + (k + 1))) * 32 + l0) = h;
}

// ---------------------------------------------------------------
// conv1 via MFMA 32x32x16: K=(d1,d2) 9-of-16, N=(d4,co), d3 folded via kk/m.
// writes PACKED X2. z = (batch<<2) | (branch<<1) | khalf   (R10 version)
// ---------------------------------------------------------------
__global__ __launch_bounds__(256) void k_conv1m(const unsigned* __restrict__ wsB1,
                                                const float* __restrict__ B1,
                                                float* ws) {
    __shared__ float epi[4][34 * 33];
    int t = threadIdx.x, lane = t & 63, wv = t >> 6;
    int zb = blockIdx.z >> 2, br = (blockIdx.z >> 1) & 1, w = blockIdx.z & 1;
    int bid = blockIdx.x;
    int s = ((bid & 7) << 7) | (bid >> 3);
    int i = s >> 5, j = s & 31;
    int k0g = w * 16 + wv * 4;           // padded-k of kk=0
    int q = lane & 31, half = lane >> 5;

    float bias[8];
#pragma unroll
    for (int e = 0; e < 8; ++e) {
        int co = half * 8 + e;
        bias[e] = (co < 10) ? B1[co] : 0.f;
    }
    if (lane < 33) { epi[wv][lane] = 0.f; epi[wv][33 * 33 + lane] = 0.f; }

    float* slot = ws + (size_t)zb * BSLOT;
    const unsigned short* XB = (const unsigned short*)(slot + OFF_XB);
    const unsigned short* xb = XB + ((size_t)((i * 34 + j) * 34 + k0g)) * 32 + q;
    const bf16x8* Bg = (const bf16x8*)(wsB1 + br * 3 * 64 * 4);

    bf16x8 A[6];
    if (half == 0) {
#pragma unroll
        for (int kk = 0; kk < 6; ++kk) {
            bf16x8 a;
#pragma unroll
            for (int e = 0; e < 8; ++e) {
                const int d1 = e / 3, d2 = e % 3;
                a[e] = (short)xb[(size_t)(d1 * 34 + d2) * 1088 + kk * 32];
            }
            A[kk] = a;
        }
    } else {
#pragma unroll
        for (int kk = 0; kk < 6; ++kk) {
            bf16x8 a = {};
            a[0] = (short)xb[(size_t)(2 * 34 + 2) * 1088 + kk * 32];
            A[kk] = a;
        }
    }
    bf16x8 Bf[3];
#pragma unroll
    for (int d3 = 0; d3 < 3; ++d3) Bf[d3] = Bg[d3 * 64 + lane];

    f32x16 D[4] = {};
#pragma unroll
    for (int kk = 0; kk < 6; ++kk)
#pragma unroll
        for (int m = 0; m < 4; ++m) {
            int d3 = kk - m;
            if (d3 >= 0 && d3 < 3)
                D[m] = __builtin_amdgcn_mfma_f32_32x32x16_bf16(A[kk], Bf[d3], D[m], 0, 0, 0);
        }

    // epilogue: d4 shift-add, bias, relu, packed store
    float* epw = epi[wv];
    char* X2b = (char*)(slot + OFF_X2 + (size_t)br * XTP);
#pragma unroll
    for (int m = 0; m < 4; ++m) {
#pragma unroll
        for (int r = 0; r < 16; ++r) {
            int row = (r & 3) + 8 * (r >> 2) + 4 * half;
            epw[(row + 1) * 33 + q] = D[m][r];
        }
        size_t lb = ((size_t)(((i + 1) * 34 + (j + 1)) * 34 + (k0g + m + 1))) * 640 + q * 20;
        if (half == 0) {
            unsigned u[4];
#pragma unroll
            for (int e = 0; e < 4; ++e) {
                unsigned short h2[2];
#pragma unroll
                for (int xx = 0; xx < 2; ++xx) {
                    int co = 2 * e + xx;
                    float v = bias[2 * e + xx];
#pragma unroll
                    for (int ss = 0; ss < 3; ++ss)
                        v += epw[(q + ss) * 33 + ss * 10 + co];
                    h2[xx] = f2bf(fmaxf(v, 0.f));
                }
                u[e] = (unsigned)h2[0] | ((unsigned)h2[1] << 16);
            }
            uintx4 u4 = {u[0], u[1], u[2], u[3]};
            *(uintx4*)(X2b + lb) = u4;
        } else {
            unsigned short h2[2];
#pragma unroll
            for (int xx = 0; xx < 2; ++xx) {
                int co = 8 + xx;
                float v = bias[xx];
#pragma unroll
                for (int ss = 0; ss < 3; ++ss)
                    v += epw[(q + ss) * 33 + ss * 10 + co];
                h2[xx] = f2bf(fmaxf(v, 0.f));
            }
            *(unsigned*)(X2b + lb + 16) = (unsigned)h2[0] | ((unsigned)h2[1] << 16);
        }
    }
}

// ---------------------------------------------------------------
// conv2 via MFMA 32x32x16, N=(d4,co). PACKED 640B A-lines, uniform loads.
// A: distance-1 ping-pong register prefetch (R10-proven).
// B: staged in LDS (27KB); epilogue scratch OVERLAYS the B-stage LDS
// (barrier before reuse) so block stays at 27KB -> same occupancy.
// Best measured variant: 131.0 us (R12).
// z = (batch<<2) | (branch<<1) | khalf
// ---------------------------------------------------------------
__global__ __launch_bounds__(256) void k_conv2m(const unsigned* __restrict__ wsB,
                                                const float* __restrict__ B2,
                                                float* ws) {
    __shared__ __align__(16) unsigned Bl[27 * 64 * 4];   // 27648 B; epi overlay after loop

    int t = threadIdx.x;
    int lane = t & 63, wv = t >> 6;
    int zb = blockIdx.z >> 2, br = (blockIdx.z >> 1) & 1, w = blockIdx.z & 1;
    int bid = blockIdx.x;
    int s = ((bid & 7) << 7) | (bid >> 3);
    int i = s >> 5, j = s & 31;
    int k0 = (w * 4 + wv) * 4;
    int q = lane & 31, half = lane >> 5;

    // stage this branch's B-pack into LDS (vectorized)
    {
        const uintx4* srcB = (const uintx4*)(wsB + br * 27 * 64 * 4);
        uintx4* dstB = (uintx4*)Bl;
#pragma unroll
        for (int idx = t; idx < 1728; idx += 256) dstB[idx] = srcB[idx];
    }

    float bias[8];
#pragma unroll
    for (int e = 0; e < 8; ++e) {
        int co = half * 8 + e;
        bias[e] = (co < 10) ? B2[co] : 0.f;
    }
    __syncthreads();

    float* slot = ws + (size_t)zb * BSLOT;
    const char* X2b = (const char*)(slot + OFF_X2 + (size_t)br * XTP)
                      + q * 20 + half * 16 + (size_t)k0 * 640;

    bf16x8 A[2][6];
    // preload tap 0
#pragma unroll
    for (int kk = 0; kk < 6; ++kk)
        A[0][kk] = *(const bf16x8*)(X2b + ((size_t)(i * 34 + j) * 34) * 640 + kk * 640);

    f32x16 D[4] = {};

#pragma unroll
    for (int g = 0; g < 9; ++g) {
        if (g < 8) {
            const int gn = g + 1, d1n = gn / 3, d2n = gn % 3;
            const char* pn = X2b + ((size_t)((i + d1n) * 34 + (j + d2n)) * 34) * 640;
#pragma unroll
            for (int kk = 0; kk < 6; ++kk)
                A[gn & 1][kk] = *(const bf16x8*)(pn + kk * 640);
        }
        bf16x8 Bf[3];
#pragma unroll
        for (int d3 = 0; d3 < 3; ++d3)
            Bf[d3] = *(const bf16x8*)&Bl[((g * 3 + d3) * 64 + lane) * 4];
#pragma unroll
        for (int kk = 0; kk < 6; ++kk)
#pragma unroll
            for (int m = 0; m < 4; ++m) {
                int d3 = kk - m;
                if (d3 >= 0 && d3 < 3)
                    D[m] = __builtin_amdgcn_mfma_f32_32x32x16_bf16(A[g & 1][kk], Bf[d3], D[m], 0, 0, 0);
            }
    }

    __syncthreads();   // all waves done reading Bl -> safe to overlay epi

    // epilogue: shift-add along d4, bias, relu, packed store to X3
    float* epw = (float*)Bl + wv * 1122;     // 34*33 floats per wave
    if (lane < 33) { epw[lane] = 0.f; epw[33 * 33 + lane] = 0.f; }
    char* X3b = (char*)(slot + OFF_X2 + (size_t)(2 + br) * XTP);
#pragma unroll
    for (int m = 0; m < 4; ++m) {
#pragma unroll
        for (int r = 0; r < 16; ++r) {
            int row = (r & 3) + 8 * (r >> 2) + 4 * half;   // D row = l
            epw[(row + 1) * 33 + q] = D[m][r];             // col = n
        }
        size_t lb = ((size_t)(((i + 1) * 34 + (j + 1)) * 34 + (k0 + m + 1))) * 640 + q * 20;
        if (half == 0) {
            unsigned u[4];
#pragma unroll
            for (int e = 0; e < 4; ++e) {
                unsigned short h2[2];
#pragma unroll
                for (int xx = 0; xx < 2; ++xx) {
                    int co = 2 * e + xx;
                    float v = bias[2 * e + xx];
#pragma unroll
                    for (int ss = 0; ss < 3; ++ss)
                        v += epw[(q + ss) * 33 + ss * 10 + co];
                    h2[xx] = f2bf(fmaxf(v, 0.f));
                }
                u[e] = (unsigned)h2[0] | ((unsigned)h2[1] << 16);
            }
            uintx4 u4 = {u[0], u[1], u[2], u[3]};
            *(uintx4*)(X3b + lb) = u4;
        } else {
            unsigned short h2[2];
#pragma unroll
            for (int xx = 0; xx < 2; ++xx) {
                int co = 8 + xx;
                float v = bias[xx];
#pragma unroll
                for (int ss = 0; ss < 3; ++ss)
                    v += epw[(q + ss) * 33 + ss * 10 + co];
                h2[xx] = f2bf(fmaxf(v, 0.f));
            }
            *(unsigned*)(X3b + lb + 16) = (unsigned)h2[0] | ((unsigned)h2[1] << 16);
        }
    }
}

// ---------------------------------------------------------------
// conv3 via MFMA, N=(d3,d4), 10->1, ReLU. BOTH branches in one block:
// out = relu(convA+b) + relu(convB+b), single coalesced store.
// PACKED A-lines, uniform loads. B from global (L1). Barrier-free. (R10)
// z = (batch<<1) | khalf
// ---------------------------------------------------------------
__global__ __launch_bounds__(256) void k_conv3m(const unsigned* __restrict__ wsB3,
                                                const float* __restrict__ B3,
                                                float* ws, float* __restrict__ out,
                                                int b0) {
    __shared__ float epi[4][6 * 34 * 9];

    int t = threadIdx.x;
    int lane = t & 63, wv = t >> 6;
    int zb = blockIdx.z >> 1, w = blockIdx.z & 1;
    int b = b0 + zb;
    int bid = blockIdx.x;
    int s = ((bid & 7) << 7) | (bid >> 3);
    int i = s >> 5, j = s & 31;
    int k0 = (w * 4 + wv) * 4;
    int q = lane & 31, half = lane >> 5;

    for (int idx = lane; idx < 6 * 9; idx += 64) {
        int rel = idx / 9, c = idx % 9;
        epi[wv][(rel * 34 + 0) * 9 + c] = 0.f;
        epi[wv][(rel * 34 + 33) * 9 + c] = 0.f;
    }

    float* slot = ws + (size_t)zb * BSLOT;
    float* epw = epi[wv];
    float bb = B3[0];
    float vsum[4];

#pragma unroll 1
    for (int br = 0; br < 2; ++br) {
        const char* X3b = (const char*)(slot + OFF_X2 + (size_t)(2 + br) * XTP)
                          + q * 20 + half * 16 + (size_t)k0 * 640;
        const bf16x8* Bg = (const bf16x8*)(wsB3 + br * 9 * 64 * 4);

        f32x16 D[6] = {};

#pragma unroll 1
        for (int g = 0; g < 9; ++g) {
            const char* pg = X3b + ((size_t)((i + g / 3) * 34 + (j + g % 3)) * 34) * 640;
            bf16x8 Bf = Bg[g * 64 + lane];
#pragma unroll
            for (int rel = 0; rel < 6; ++rel) {
                bf16x8 A = *(const bf16x8*)(pg + rel * 640);
                D[rel] = __builtin_amdgcn_mfma_f32_32x32x16_bf16(A, Bf, D[rel], 0, 0, 0);
            }
        }

        if (q < 9) {
#pragma unroll
            for (int rel = 0; rel < 6; ++rel)
#pragma unroll
                for (int r = 0; r < 16; ++r) {
                    int row = (r & 3) + 8 * (r >> 2) + 4 * half;
                    epw[(rel * 34 + row + 1) * 9 + q] = D[rel][r];
                }
        }
        // per-wave LDS: within-wave in-order LDS suffices (no barrier)
#pragma unroll
        for (int m = 0; m < 4; ++m) {
            float v = bb;
#pragma unroll
            for (int d3 = 0; d3 < 3; ++d3)
#pragma unroll
                for (int d4 = 0; d4 < 3; ++d4)
                    v += epw[((m + d3) * 34 + (q + d4)) * 9 + d3 * 3 + d4];
            v = fmaxf(v, 0.f);
            if (br == 0) vsum[m] = v; else vsum[m] += v;
        }
    }

    float* dst = out + (size_t)b * NPTS;
    if (half == 0)
#pragma unroll
        for (int m = 0; m < 4; ++m)
            dst[(size_t)i * 32768 + j * 1024 + (k0 + m) * 32 + q] = vsum[m];
}

// ---------------------------------------------------------------
extern "C" void kernel_launch(void* const* d_in, const int* in_sizes, int n_in,
                              void* d_out, int out_size, void* d_ws, size_t ws_size,
                              hipStream_t stream) {
    const float* x  = (const float*)d_in[0];
    const float* W1 = (const float*)d_in[1];
    const float* b1 = (const float*)d_in[2];
    const float* W2 = (const float*)d_in[3];
    const float* b2 = (const float*)d_in[4];
    const float* W3 = (const float*)d_in[5];
    const float* b3 = (const float*)d_in[6];
    float* out = (float*)d_out;
    float* ws  = (float*)d_ws;
    float* slots = ws + WSB_FLOATS;
    unsigned* wsB2 = (unsigned*)ws;
    unsigned* wsB3 = (unsigned*)ws + 13824;
    unsigned* wsB1 = (unsigned*)ws + 18432;

    size_t slot_bytes = BSLOT * sizeof(float);
    int GB = (int)((ws_size - WSB_FLOATS * 4) / slot_bytes);
    if (GB > 4) GB = 4;
    if (GB < 1) GB = 1;

    k_zero_halo<<<dim3((NHALO + 3) / 4, GB), 256, 0, stream>>>(slots);
    k_bpack_all<<<1, 256, 0, stream>>>(W1, W2, W3, wsB2, wsB3, wsB1);

    for (int b0 = 0; b0 < 4; b0 += GB) {
        int gb = 4 - b0 < GB ? 4 - b0 : GB;
        k_copy_in<<<dim3(1024, 1, gb), 256, 0, stream>>>(x, slots, b0);
        k_conv1m<<<dim3(1024, 1, 4 * gb), 256, 0, stream>>>(wsB1, b1, slots);
        k_conv2m<<<dim3(1024, 1, 4 * gb), 256, 0, stream>>>(wsB2, b2, slots);
        k_conv3m<<<dim3(1024, 1, 2 * gb), 256, 0, stream>>>(wsB3, b3, slots, out, b0);
    }
}